// Round 13
// baseline (525.265 us; speedup 1.0000x reference)
//
#include <hip/hip_runtime.h>
#include <hip/hip_bf16.h>

// LocalBlock: tpose+LN1 -> qkv GEMM -> multi-dilate attn(+xn) -> proj GEMM(+x, bf16 y)
//            -> LN2 -> fc1+gelu -> fc2(+y, transposed f32 out)
// GEMM: BM=128 BN=192 BK=32, 512 thr (8 waves 2m x 4n, wave-tile 64x48, acc[4][3]),
//       LDS ring-2 x 20KB = 40KB, __launch_bounds__(512,6) -> 3 blocks/CU (24 waves),
//       counted vmcnt, 2 barriers/iter, compile-time staging, conflict-free swizzle,
//       bijective XCD m-band swizzle.

#define B_   8
#define C_   384
#define W_   56
#define HW_  3136
#define N_   25088
#define HID_ 1536
#define C3_  1152

typedef __attribute__((ext_vector_type(8))) short short8v;
typedef __attribute__((ext_vector_type(4))) float f32x4;
typedef __attribute__((ext_vector_type(4))) unsigned short ushort4v;

__device__ __forceinline__ float bf2f(unsigned short u) {
  union { float f; unsigned u; } c; c.u = ((unsigned)u) << 16; return c.f;
}
__device__ __forceinline__ unsigned short f2bf(float f) {
  unsigned u = __float_as_uint(f);
  u = (u + 0x7FFFu + ((u >> 16) & 1u)) >> 16;
  return (unsigned short)u;
}
__device__ __forceinline__ float gelu_fast(float x) {
  const float z = 1.5957691216057308f * (x + 0.044715f * x * x * x);
  return x / (1.f + __expf(-z));
}

#define GLL(gsrc, ldst) __builtin_amdgcn_global_load_lds( \
    (const __attribute__((address_space(1))) void*)(gsrc), \
    (__attribute__((address_space(3))) void*)(ldst), 16, 0, 0)

// ---------------- weight fp32 -> bf16 (plain [n][k]) ----------------
__global__ void cvt_weights(const float* __restrict__ qw, const float* __restrict__ pw,
                            const float* __restrict__ f1, const float* __restrict__ f2,
                            unsigned short* __restrict__ o) {
  int i = blockIdx.x * 256 + threadIdx.x;
  if (i < 442368)        o[i] = f2bf(qw[i]);
  else if (i < 589824)   o[i] = f2bf(pw[i - 442368]);
  else if (i < 1179648)  o[i] = f2bf(f1[i - 589824]);
  else if (i < 1769472)  o[i] = f2bf(f2[i - 1179648]);
}

// ---------------- fused transpose + LN1: x[B,C,HW] -> xpb[N,C] bf16, xn[N,C] bf16 ---------
__global__ __launch_bounds__(256)
void tpose_ln(const float* __restrict__ x, unsigned short* __restrict__ xpb,
              unsigned short* __restrict__ xnb,
              const float* __restrict__ gam, const float* __restrict__ bet) {
  __shared__ float ft[64][385];
  __shared__ float mstat[64], rstat[64];
  const int tid = threadIdx.x;
  const int nb0 = blockIdx.x * 64;
  const int bb = nb0 / HW_, hw0 = nb0 - bb * HW_;
  const float* xb = x + (size_t)bb * C_ * HW_ + hw0;
#pragma unroll
  for (int p = 0; p < 24; ++p) {
    const int c = p * 16 + (tid >> 4);
    f32x4 v = *(const f32x4*)&xb[(size_t)c * HW_ + (tid & 15) * 4];
#pragma unroll
    for (int j = 0; j < 4; ++j) ft[(tid & 15) * 4 + j][c] = v[j];
  }
  __syncthreads();
  const int l16 = tid & 15, g16 = tid >> 4;
#pragma unroll
  for (int rr = 0; rr < 4; ++rr) {
    const int row = g16 * 4 + rr;
    float s = 0.f, ss = 0.f;
#pragma unroll
    for (int k2 = 0; k2 < 24; ++k2) { float v = ft[row][l16 + k2 * 16]; s += v; ss += v * v; }
    s += __shfl_xor(s, 8); ss += __shfl_xor(ss, 8);
    s += __shfl_xor(s, 4); ss += __shfl_xor(ss, 4);
    s += __shfl_xor(s, 2); ss += __shfl_xor(ss, 2);
    s += __shfl_xor(s, 1); ss += __shfl_xor(ss, 1);
    if (l16 == 0) {
      const float mean = s * (1.f / 384.f);
      const float var = ss * (1.f / 384.f) - mean * mean;
      mstat[row] = mean; rstat[row] = rsqrtf(var + 1e-5f);
    }
  }
  __syncthreads();
  const int row = tid >> 2, part = tid & 3;
  const float mean = mstat[row], rstd = rstat[row];
  unsigned short* xpr = xpb + (size_t)(nb0 + row) * C_ + part * 96;
  unsigned short* xr = xnb + (size_t)(nb0 + row) * C_ + part * 96;
#pragma unroll
  for (int q = 0; q < 12; ++q) {
    short8v oraw, oln;
#pragma unroll
    for (int e = 0; e < 8; ++e) {
      const int c = part * 96 + q * 8 + e;
      const float v = ft[row][c];
      oraw[e] = (short)f2bf(v);
      oln[e] = (short)f2bf((v - mean) * rstd * gam[c] + bet[c]);
    }
    *(short8v*)&xpr[q * 8] = oraw;
    *(short8v*)&xr[q * 8] = oln;
  }
}

// ---------------- row LayerNorm bf16 -> bf16 (LN2) ----------------
__global__ __launch_bounds__(256)
void ln_rows(const unsigned short* __restrict__ in, unsigned short* __restrict__ outb,
             const float* __restrict__ g, const float* __restrict__ bb) {
  const int row = blockIdx.x * 4 + (threadIdx.x >> 6);
  const int l = threadIdx.x & 63;
  float v[8]; float s = 0.f, ss = 0.f;
  if (l < 48) {
    short8v r = *(const short8v*)&in[(size_t)row * C_ + l * 8];
#pragma unroll
    for (int e = 0; e < 8; ++e) { v[e] = bf2f((unsigned short)r[e]); s += v[e]; ss += v[e] * v[e]; }
  }
#pragma unroll
  for (int off = 32; off; off >>= 1) { s += __shfl_xor(s, off); ss += __shfl_xor(ss, off); }
  const float mean = s * (1.f / 384.f);
  const float var = ss * (1.f / 384.f) - mean * mean;
  const float rstd = rsqrtf(var + 1e-5f);
  if (l < 48) {
    short8v o;
#pragma unroll
    for (int e = 0; e < 8; ++e) {
      const int c = l * 8 + e;
      o[e] = (short)f2bf((v[e] - mean) * rstd * g[c] + bb[c]);
    }
    *(short8v*)&outb[(size_t)row * C_ + l * 8] = o;
  }
}

// ---------------- GEMM: out[M,NOUT] = A[M,K] @ W[NOUT,K]^T ----------------
// MODE 0: bf16 out (qkv, no bias)        MODE 1: bf16 out = resid + v + bias (proj)
// MODE 2: bf16 out = gelu(v+bias) (fc1)  MODE 3: f32 d_out[B,C,HW] = resid+v+bias transposed
template <int MODE, int NOUT, int K>
__global__ __launch_bounds__(512, 6)
void gemmW(const unsigned short* __restrict__ A, const unsigned short* __restrict__ Wt,
           const float* __restrict__ bias, const unsigned short* __restrict__ resid,
           void* __restrict__ outp) {
  constexpr bool SWAP = (MODE != 3);
  constexpr int KT = K / 32;
  constexpr int SLOTU = 320 * 32;            // 20 KB per slot
  __shared__ unsigned short sm[2 * SLOTU];   // 40 KiB ring-2 -> 3 blocks/CU at (512,6)
  const int tid = threadIdx.x, l = tid & 63, wv = tid >> 6;
  const int wm = wv >> 2, wn = wv & 3;

  // bijective XCD swizzle (nwg % 8 == 0 for all grids), m-band contiguous per XCD
  const int nx = gridDim.x;
  const int nwg = nx * gridDim.y;
  const int bid = blockIdx.y * nx + blockIdx.x;
  const int wg = (bid & 7) * (nwg >> 3) + (bid >> 3);
  const int m0 = (wg / nx) * 128, n0 = (wg % nx) * 192;

  // staging, compile-time chunk counts: waves 0..3 -> A chunks {2wv, 2wv+1};
  // waves 4..7 -> B chunks {8+3(wv-4) .. +2}.  chunk c: rows c*16 + (l>>2).
  const int cg = (((l & 3) ^ ((l >> 3) & 3)) << 3);   // inverse-swizzled source col
  const int c0 = (wv < 4) ? (2 * wv) : (8 + 3 * (wv - 4));
  const int r0 = c0 * 16 + (l >> 2);
  const unsigned short* p0;
  const unsigned short* p1;
  const unsigned short* p2;
  if (wv < 4) {
    p0 = A + (size_t)(m0 + r0) * K + cg;
    p1 = A + (size_t)(m0 + r0 + 16) * K + cg;
    p2 = p0;
  } else {
    p0 = Wt + (size_t)(n0 + (r0 - 128)) * K + cg;
    p1 = Wt + (size_t)(n0 + (r0 - 128) + 16) * K + cg;
    p2 = Wt + (size_t)(n0 + (r0 - 128) + 32) * K + cg;
  }
  const int d0 = c0 * 512 + l * 8, d1 = d0 + 512, d2 = d0 + 1024;

  auto stage = [&](int t) {
    const int sb = (t & 1) * SLOTU;
    if (wv < 4) {
      GLL(p0 + t * 32, &sm[sb + d0]);
      GLL(p1 + t * 32, &sm[sb + d1]);
    } else {
      GLL(p0 + t * 32, &sm[sb + d0]);
      GLL(p1 + t * 32, &sm[sb + d1]);
      GLL(p2 + t * 32, &sm[sb + d2]);
    }
  };

  // fragment read offsets (swizzled): s = fr*4 + (g ^ ((fr>>1)&3))
  const int fr = l & 15, g = l >> 4, g4 = g * 4;
  const int sfr = (fr * 4 + (g ^ ((fr >> 1) & 3))) * 8;
  int aoff[4], boff[3];
#pragma unroll
  for (int mt = 0; mt < 4; ++mt) aoff[mt] = (wm * 4 + mt) * 512 + sfr;
#pragma unroll
  for (int nt = 0; nt < 3; ++nt) boff[nt] = (8 + wn * 3 + nt) * 512 + sfr;

  f32x4 acc[4][3] = {};

  stage(0);
  for (int t = 0; t < KT; ++t) {
    __builtin_amdgcn_s_barrier();            // slot (t+1)&1 free: reads of t-1 done
    __builtin_amdgcn_sched_barrier(0);
    if (t + 1 < KT) {
      stage(t + 1);
      __builtin_amdgcn_sched_barrier(0);
      if (wv < 4) asm volatile("s_waitcnt vmcnt(2)" ::: "memory");
      else        asm volatile("s_waitcnt vmcnt(3)" ::: "memory");
    } else {
      asm volatile("s_waitcnt vmcnt(0)" ::: "memory");
    }
    __builtin_amdgcn_sched_barrier(0);
    __builtin_amdgcn_s_barrier();            // slot t fully staged for all waves
    __builtin_amdgcn_sched_barrier(0);
    const int sb = (t & 1) * SLOTU;
    short8v av[4], bv[3];
#pragma unroll
    for (int mt = 0; mt < 4; ++mt) av[mt] = *(const short8v*)&sm[sb + aoff[mt]];
#pragma unroll
    for (int nt = 0; nt < 3; ++nt) bv[nt] = *(const short8v*)&sm[sb + boff[nt]];
    __builtin_amdgcn_s_setprio(1);
#pragma unroll
    for (int mt = 0; mt < 4; ++mt)
#pragma unroll
      for (int nt = 0; nt < 3; ++nt)
        acc[mt][nt] = SWAP
          ? __builtin_amdgcn_mfma_f32_16x16x32_bf16(bv[nt], av[mt], acc[mt][nt], 0, 0, 0)
          : __builtin_amdgcn_mfma_f32_16x16x32_bf16(av[mt], bv[nt], acc[mt][nt], 0, 0, 0);
    __builtin_amdgcn_s_setprio(0);
    __builtin_amdgcn_sched_barrier(0);
  }
  __syncthreads();   // K-loop done everywhere; sm reusable for epilogue

  if constexpr (SWAP) {
    // lane: m(local) = wm*64 + mt*16 + fr ; n(local) = wn*48 + nt*16 + g4 + j
    // two half-tile passes (64 rows each) through padded LDS [64][200] bf16
    unsigned short* op = (unsigned short*)outp;
#pragma unroll
    for (int half = 0; half < 2; ++half) {
      if (wm == half) {
#pragma unroll
        for (int mt = 0; mt < 4; ++mt) {
          const int ml = mt * 16 + fr;
#pragma unroll
          for (int nt = 0; nt < 3; ++nt) {
            const int nl = wn * 48 + nt * 16 + g4;
            f32x4 v = acc[mt][nt];
            ushort4v pk;
#pragma unroll
            for (int j = 0; j < 4; ++j) pk[j] = f2bf(v[j]);
            *(ushort4v*)&sm[ml * 200 + nl] = pk;
          }
        }
      }
      __syncthreads();
#pragma unroll
      for (int it = 0; it < 3; ++it) {
        const int slot = it * 512 + tid;     // 64 rows x 24 groups
        const int row = slot / 24, grp = slot - row * 24;
        const int mg = m0 + half * 64 + row;
        const int n = n0 + grp * 8;
        short8v v = *(const short8v*)&sm[row * 200 + grp * 8];
        if constexpr (MODE == 2) {
          const f32x4 b0 = *(const f32x4*)&bias[n];
          const f32x4 b1 = *(const f32x4*)&bias[n + 4];
#pragma unroll
          for (int e = 0; e < 8; ++e) {
            const float xv = bf2f((unsigned short)v[e]) + (e < 4 ? b0[e] : b1[e - 4]);
            v[e] = (short)f2bf(gelu_fast(xv));
          }
        } else if constexpr (MODE == 1) {
          const f32x4 b0 = *(const f32x4*)&bias[n];
          const f32x4 b1 = *(const f32x4*)&bias[n + 4];
          const short8v r8 = *(const short8v*)&resid[(size_t)mg * C_ + n];
#pragma unroll
          for (int e = 0; e < 8; ++e)
            v[e] = (short)f2bf(bf2f((unsigned short)v[e]) + (e < 4 ? b0[e] : b1[e - 4])
                               + bf2f((unsigned short)r8[e]));
        }
        *(short8v*)&op[(size_t)mg * NOUT + n] = v;
      }
      __syncthreads();
    }
  } else {
    // MODE 3: lane: m = m0 + wm*64 + mt*16 + g4 + j ; c = n0 + wn*48 + nt*16 + fr
    // four 48-col passes through f32 LDS [48 c][32 u], swizzled, coalesced stores
    float* lf = (float*)sm;
    float* out = (float*)outp;
#pragma unroll
    for (int q = 0; q < 4; ++q) {
      if (wn == q) {
#pragma unroll
        for (int mt = 0; mt < 4; ++mt) {
          const int u = wm * 16 + mt * 4 + g;
#pragma unroll
          for (int nt = 0; nt < 3; ++nt) {
            const int cl = nt * 16 + fr;
            const int cgl = n0 + q * 48 + cl;
            const float bo = bias[cgl];
            f32x4 v = acc[mt][nt];
#pragma unroll
            for (int j = 0; j < 4; ++j)
              v[j] = v[j] + bo + bf2f(resid[(size_t)(m0 + u * 4 + j) * C_ + cgl]);
            *(f32x4*)&lf[cl * 128 + ((u ^ (cl & 7)) << 2)] = v;
          }
        }
      }
      __syncthreads();
#pragma unroll
      for (int it = 0; it < 3; ++it) {
        const int slot = it * 512 + tid;     // 48 cols x 32 row-chunks
        const int u = slot & 31, cl = slot >> 5;
        f32x4 v = *(const f32x4*)&lf[cl * 128 + ((u ^ (cl & 7)) << 2)];
        const int cgl = n0 + q * 48 + cl;
        const int mg = m0 + u * 4;
        const int bb = mg / HW_, hw = mg - bb * HW_;
        *(f32x4*)&out[((size_t)bb * C_ + cgl) * HW_ + hw] = v;
      }
      __syncthreads();
    }
  }
}

// ---------------- multi-dilate local attention (+xn) ----------------
__global__ __launch_bounds__(256)
void attn_kernel(const unsigned short* __restrict__ qkv,
                 const unsigned short* __restrict__ xn,
                 unsigned short* __restrict__ aout) {
  const int gid = blockIdx.x * 256 + threadIdx.x;
  const int n = gid / 12;
  const int r = gid - n * 12;
  const int dil = (r >> 2) + 1;
  const int b = n / HW_;
  const int hw = n - b * HW_;
  const int h = hw / W_;
  const int w = hw - h * W_;

  const size_t base = (size_t)n * C3_ + (size_t)r * 32;
  float q[32];
  {
    const short8v* vp = (const short8v*)(qkv + base);
#pragma unroll
    for (int c8 = 0; c8 < 4; ++c8) {
      short8v v = vp[c8];
#pragma unroll
      for (int e = 0; e < 8; ++e) q[c8 * 8 + e] = bf2f((unsigned short)v[e]);
    }
  }

  float logit[9];
#pragma unroll
  for (int ti = 0; ti < 3; ++ti)
#pragma unroll
    for (int tj = 0; tj < 3; ++tj) {
      const int t = ti * 3 + tj;
      const int hn = h + (ti - 1) * dil, wn = w + (tj - 1) * dil;
      if ((unsigned)hn < 56u && (unsigned)wn < 56u) {
        const int nb = n + (ti - 1) * dil * W_ + (tj - 1) * dil;
        const short8v* kp = (const short8v*)(qkv + (size_t)nb * C3_ + C_ + (size_t)r * 32);
        float dot = 0.f;
#pragma unroll
        for (int c8 = 0; c8 < 4; ++c8) {
          short8v v = kp[c8];
#pragma unroll
          for (int e = 0; e < 8; ++e) dot += q[c8 * 8 + e] * bf2f((unsigned short)v[e]);
        }
        logit[t] = dot * 0.17677669529663688f;
      } else {
        logit[t] = 0.f;  // zero-padded taps participate with logit 0
      }
    }

  float mx = logit[0];
#pragma unroll
  for (int t = 1; t < 9; ++t) mx = fmaxf(mx, logit[t]);
  float wgt[9]; float se = 0.f;
#pragma unroll
  for (int t = 0; t < 9; ++t) { wgt[t] = __expf(logit[t] - mx); se += wgt[t]; }
  const float inv = 1.f / se;

  float acc[32];
#pragma unroll
  for (int c = 0; c < 32; ++c) acc[c] = 0.f;
#pragma unroll
  for (int ti = 0; ti < 3; ++ti)
#pragma unroll
    for (int tj = 0; tj < 3; ++tj) {
      const int t = ti * 3 + tj;
      const int hn = h + (ti - 1) * dil, wn = w + (tj - 1) * dil;
      if ((unsigned)hn < 56u && (unsigned)wn < 56u) {
        const int nb = n + (ti - 1) * dil * W_ + (tj - 1) * dil;
        const short8v* vp = (const short8v*)(qkv + (size_t)nb * C3_ + 2 * C_ + (size_t)r * 32);
        const float wt = wgt[t];
#pragma unroll
        for (int c8 = 0; c8 < 4; ++c8) {
          short8v v = vp[c8];
#pragma unroll
          for (int e = 0; e < 8; ++e) acc[c8 * 8 + e] += wt * bf2f((unsigned short)v[e]);
        }
      }
    }

  const size_t obase = (size_t)n * C_ + (size_t)r * 32;
  const short8v* xv = (const short8v*)(xn + obase);
  short8v ov[4];
#pragma unroll
  for (int c8 = 0; c8 < 4; ++c8) {
    short8v v = xv[c8];
#pragma unroll
    for (int e = 0; e < 8; ++e)
      ov[c8][e] = (short)f2bf(acc[c8 * 8 + e] * inv + bf2f((unsigned short)v[e]));
  }
  short8v* op = (short8v*)(aout + obase);
#pragma unroll
  for (int c8 = 0; c8 < 4; ++c8) op[c8] = ov[c8];
}

extern "C" void kernel_launch(void* const* d_in, const int* in_sizes, int n_in,
                              void* d_out, int out_size, void* d_ws, size_t ws_size,
                              hipStream_t stream) {
  const float* x = (const float*)d_in[0];
  const float* qkv_w = (const float*)d_in[1];
  const float* proj_w = (const float*)d_in[2];
  const float* proj_b = (const float*)d_in[3];
  const float* n1_g = (const float*)d_in[4];
  const float* n1_b = (const float*)d_in[5];
  const float* n2_g = (const float*)d_in[6];
  const float* n2_b = (const float*)d_in[7];
  const float* fc1_w = (const float*)d_in[8];
  const float* fc1_b = (const float*)d_in[9];
  const float* fc2_w = (const float*)d_in[10];
  const float* fc2_b = (const float*)d_in[11];

  char* ws = (char*)d_ws;
  unsigned short* xpb = (unsigned short*)ws;                     // [N,C] bf16 (x transposed)
  unsigned short* xn = (unsigned short*)(ws + 19267584);         // [N,C] bf16 (LN1/LN2 out)
  unsigned short* qkvb = (unsigned short*)(ws + 38535168);       // [N,1152] bf16
  unsigned short* abuf = (unsigned short*)(ws + 96337920);       // [N,C] bf16
  unsigned short* y = (unsigned short*)(ws + 115605504);         // [N,C] bf16 residual stream
  unsigned short* hbuf = qkvb;                                   // [N,1536] bf16 (reuse)
  unsigned short* wq = (unsigned short*)(ws + 134873088);        // weights bf16 [n][k]
  unsigned short* wp = wq + 442368;
  unsigned short* wf1 = wp + 147456;
  unsigned short* wf2 = wf1 + 589824;

  cvt_weights<<<6912, 256, 0, stream>>>(qkv_w, proj_w, fc1_w, fc2_w, wq);
  tpose_ln<<<392, 256, 0, stream>>>(x, xpb, xn, n1_g, n1_b);
  gemmW<0, C3_, C_><<<dim3(6, 196), 512, 0, stream>>>(xn, wq, nullptr, nullptr, qkvb);
  attn_kernel<<<1176, 256, 0, stream>>>(qkvb, xn, abuf);
  gemmW<1, C_, C_><<<dim3(2, 196), 512, 0, stream>>>(abuf, wp, proj_b, xpb, y);
  ln_rows<<<6272, 256, 0, stream>>>(y, xn, n2_g, n2_b);
  gemmW<2, HID_, C_><<<dim3(8, 196), 512, 0, stream>>>(xn, wf1, fc1_b, nullptr, hbuf);
  gemmW<3, C_, HID_><<<dim3(2, 196), 512, 0, stream>>>(hbuf, wf2, fc2_b, y, d_out);
}

// Round 14
// 258.625 us; speedup vs baseline: 2.0310x; 2.0310x over previous
//
#include <hip/hip_runtime.h>
#include <hip/hip_bf16.h>

// LocalBlock: tpose+LN1 -> qkv GEMM -> multi-dilate attn(+xn) -> proj GEMM(+x, bf16 y)
//            -> LN2 -> fc1+gelu -> fc2(+y, transposed f32 out)
// GEMM: BM=128 BN=192 **BK=64**, 512 thr (8 waves 2m x 4n, wave-tile 64x48, acc[4][3]),
//       LDS ring-2 x 40KB = 80KB, launch_bounds(512,4), counted vmcnt, 2 barriers/step,
//       two kh-phases per step (24 MFMA/wave), conflict-free swizzle, XCD m-band swizzle.
// Single-variable experiment vs round 8: halve barrier-step count at constant bytes.

#define B_   8
#define C_   384
#define W_   56
#define HW_  3136
#define N_   25088
#define HID_ 1536
#define C3_  1152

typedef __attribute__((ext_vector_type(8))) short short8v;
typedef __attribute__((ext_vector_type(4))) float f32x4;
typedef __attribute__((ext_vector_type(4))) unsigned short ushort4v;

__device__ __forceinline__ float bf2f(unsigned short u) {
  union { float f; unsigned u; } c; c.u = ((unsigned)u) << 16; return c.f;
}
__device__ __forceinline__ unsigned short f2bf(float f) {
  unsigned u = __float_as_uint(f);
  u = (u + 0x7FFFu + ((u >> 16) & 1u)) >> 16;
  return (unsigned short)u;
}
__device__ __forceinline__ float gelu_fast(float x) {
  const float z = 1.5957691216057308f * (x + 0.044715f * x * x * x);
  return x / (1.f + __expf(-z));
}

#define GLL(gsrc, ldst) __builtin_amdgcn_global_load_lds( \
    (const __attribute__((address_space(1))) void*)(gsrc), \
    (__attribute__((address_space(3))) void*)(ldst), 16, 0, 0)

// ---------------- weight fp32 -> bf16 (plain [n][k]) ----------------
__global__ void cvt_weights(const float* __restrict__ qw, const float* __restrict__ pw,
                            const float* __restrict__ f1, const float* __restrict__ f2,
                            unsigned short* __restrict__ o) {
  int i = blockIdx.x * 256 + threadIdx.x;
  if (i < 442368)        o[i] = f2bf(qw[i]);
  else if (i < 589824)   o[i] = f2bf(pw[i - 442368]);
  else if (i < 1179648)  o[i] = f2bf(f1[i - 589824]);
  else if (i < 1769472)  o[i] = f2bf(f2[i - 1179648]);
}

// ---------------- fused transpose + LN1: x[B,C,HW] -> xpb[N,C] bf16, xn[N,C] bf16 ---------
__global__ __launch_bounds__(256)
void tpose_ln(const float* __restrict__ x, unsigned short* __restrict__ xpb,
              unsigned short* __restrict__ xnb,
              const float* __restrict__ gam, const float* __restrict__ bet) {
  __shared__ float ft[64][385];
  __shared__ float mstat[64], rstat[64];
  const int tid = threadIdx.x;
  const int nb0 = blockIdx.x * 64;
  const int bb = nb0 / HW_, hw0 = nb0 - bb * HW_;
  const float* xb = x + (size_t)bb * C_ * HW_ + hw0;
#pragma unroll
  for (int p = 0; p < 24; ++p) {
    const int c = p * 16 + (tid >> 4);
    f32x4 v = *(const f32x4*)&xb[(size_t)c * HW_ + (tid & 15) * 4];
#pragma unroll
    for (int j = 0; j < 4; ++j) ft[(tid & 15) * 4 + j][c] = v[j];
  }
  __syncthreads();
  const int l16 = tid & 15, g16 = tid >> 4;
#pragma unroll
  for (int rr = 0; rr < 4; ++rr) {
    const int row = g16 * 4 + rr;
    float s = 0.f, ss = 0.f;
#pragma unroll
    for (int k2 = 0; k2 < 24; ++k2) { float v = ft[row][l16 + k2 * 16]; s += v; ss += v * v; }
    s += __shfl_xor(s, 8); ss += __shfl_xor(ss, 8);
    s += __shfl_xor(s, 4); ss += __shfl_xor(ss, 4);
    s += __shfl_xor(s, 2); ss += __shfl_xor(ss, 2);
    s += __shfl_xor(s, 1); ss += __shfl_xor(ss, 1);
    if (l16 == 0) {
      const float mean = s * (1.f / 384.f);
      const float var = ss * (1.f / 384.f) - mean * mean;
      mstat[row] = mean; rstat[row] = rsqrtf(var + 1e-5f);
    }
  }
  __syncthreads();
  const int row = tid >> 2, part = tid & 3;
  const float mean = mstat[row], rstd = rstat[row];
  unsigned short* xpr = xpb + (size_t)(nb0 + row) * C_ + part * 96;
  unsigned short* xr = xnb + (size_t)(nb0 + row) * C_ + part * 96;
#pragma unroll
  for (int q = 0; q < 12; ++q) {
    short8v oraw, oln;
#pragma unroll
    for (int e = 0; e < 8; ++e) {
      const int c = part * 96 + q * 8 + e;
      const float v = ft[row][c];
      oraw[e] = (short)f2bf(v);
      oln[e] = (short)f2bf((v - mean) * rstd * gam[c] + bet[c]);
    }
    *(short8v*)&xpr[q * 8] = oraw;
    *(short8v*)&xr[q * 8] = oln;
  }
}

// ---------------- row LayerNorm bf16 -> bf16 (LN2) ----------------
__global__ __launch_bounds__(256)
void ln_rows(const unsigned short* __restrict__ in, unsigned short* __restrict__ outb,
             const float* __restrict__ g, const float* __restrict__ bb) {
  const int row = blockIdx.x * 4 + (threadIdx.x >> 6);
  const int l = threadIdx.x & 63;
  float v[8]; float s = 0.f, ss = 0.f;
  if (l < 48) {
    short8v r = *(const short8v*)&in[(size_t)row * C_ + l * 8];
#pragma unroll
    for (int e = 0; e < 8; ++e) { v[e] = bf2f((unsigned short)r[e]); s += v[e]; ss += v[e] * v[e]; }
  }
#pragma unroll
  for (int off = 32; off; off >>= 1) { s += __shfl_xor(s, off); ss += __shfl_xor(ss, off); }
  const float mean = s * (1.f / 384.f);
  const float var = ss * (1.f / 384.f) - mean * mean;
  const float rstd = rsqrtf(var + 1e-5f);
  if (l < 48) {
    short8v o;
#pragma unroll
    for (int e = 0; e < 8; ++e) {
      const int c = l * 8 + e;
      o[e] = (short)f2bf((v[e] - mean) * rstd * g[c] + bb[c]);
    }
    *(short8v*)&outb[(size_t)row * C_ + l * 8] = o;
  }
}

// ---------------- GEMM: out[M,NOUT] = A[M,K] @ W[NOUT,K]^T ----------------
// MODE 0: bf16 out (qkv, no bias)        MODE 1: bf16 out = resid + v + bias (proj)
// MODE 2: bf16 out = gelu(v+bias) (fc1)  MODE 3: f32 d_out[B,C,HW] = resid+v+bias transposed
template <int MODE, int NOUT, int K>
__global__ __launch_bounds__(512, 4)
void gemmW(const unsigned short* __restrict__ A, const unsigned short* __restrict__ Wt,
           const float* __restrict__ bias, const unsigned short* __restrict__ resid,
           void* __restrict__ outp) {
  constexpr bool SWAP = (MODE != 3);
  constexpr int KT = K / 64;                 // 6 (K=384) or 24 (K=1536)
  constexpr int SLOTU = 640 * 32;            // 40 KB per slot: 40 chunks x 512 ushort
  __shared__ unsigned short sm[2 * SLOTU];   // 80 KiB ring-2
  const int tid = threadIdx.x, l = tid & 63, wv = tid >> 6;
  const int wm = wv >> 2, wn = wv & 3;

  // bijective XCD swizzle (nwg % 8 == 0 for all grids), m-band contiguous per XCD
  const int nx = gridDim.x;
  const int nwg = nx * gridDim.y;
  const int bid = blockIdx.y * nx + blockIdx.x;
  const int wg = (bid & 7) * (nwg >> 3) + (bid >> 3);
  const int m0 = (wg / nx) * 128, n0 = (wg % nx) * 192;

  // staging: per kh-half 20 chunks (A: 0..7 rows m0+16c.., B: 8..19 rows n0+16(c-8)..)
  // waves 0..3 -> A chunks {2wv, 2wv+1}; waves 4..7 -> B chunks {8+3(wv-4)..+2}
  // chunk c covers rows c*16 + (l>>2); lane source col-group = (l&3)^((l>>3)&3)  [inv swz]
  const int cg = (((l & 3) ^ ((l >> 3) & 3)) << 3);
  const int c0 = (wv < 4) ? (2 * wv) : (8 + 3 * (wv - 4));
  const int r0 = c0 * 16 + (l >> 2);
  const unsigned short* p0;
  const unsigned short* p1;
  const unsigned short* p2;
  if (wv < 4) {
    p0 = A + (size_t)(m0 + r0) * K + cg;
    p1 = A + (size_t)(m0 + r0 + 16) * K + cg;
    p2 = p0;
  } else {
    p0 = Wt + (size_t)(n0 + (r0 - 128)) * K + cg;
    p1 = Wt + (size_t)(n0 + (r0 - 128) + 16) * K + cg;
    p2 = Wt + (size_t)(n0 + (r0 - 128) + 32) * K + cg;
  }
  const int d0 = c0 * 512 + l * 8, d1 = d0 + 512, d2 = d0 + 1024;

  auto stage = [&](int t) {
    const int sb = (t & 1) * SLOTU;
    const size_t ko = (size_t)t * 64;
    if (wv < 4) {
      GLL(p0 + ko, &sm[sb + d0]);
      GLL(p1 + ko, &sm[sb + d1]);
      GLL(p0 + ko + 32, &sm[sb + d0 + 10240]);   // kh1 half
      GLL(p1 + ko + 32, &sm[sb + d1 + 10240]);
    } else {
      GLL(p0 + ko, &sm[sb + d0]);
      GLL(p1 + ko, &sm[sb + d1]);
      GLL(p2 + ko, &sm[sb + d2]);
      GLL(p0 + ko + 32, &sm[sb + d0 + 10240]);
      GLL(p1 + ko + 32, &sm[sb + d1 + 10240]);
      GLL(p2 + ko + 32, &sm[sb + d2 + 10240]);
    }
  };

  // fragment read offsets (swizzled): s = fr*4 + (g ^ ((fr>>1)&3)); kh1 adds 10240
  const int fr = l & 15, g = l >> 4, g4 = g * 4;
  const int sfr = (fr * 4 + (g ^ ((fr >> 1) & 3))) * 8;
  int aoff[4], boff[3];
#pragma unroll
  for (int mt = 0; mt < 4; ++mt) aoff[mt] = (wm * 4 + mt) * 512 + sfr;
#pragma unroll
  for (int nt = 0; nt < 3; ++nt) boff[nt] = (8 + wn * 3 + nt) * 512 + sfr;

  f32x4 acc[4][3] = {};

  stage(0);
  for (int t = 0; t < KT; ++t) {
    __builtin_amdgcn_s_barrier();            // slot (t+1)&1 free: reads of t-1 done
    __builtin_amdgcn_sched_barrier(0);
    if (t + 1 < KT) {
      stage(t + 1);
      __builtin_amdgcn_sched_barrier(0);
      if (wv < 4) asm volatile("s_waitcnt vmcnt(4)" ::: "memory");
      else        asm volatile("s_waitcnt vmcnt(6)" ::: "memory");
    } else {
      asm volatile("s_waitcnt vmcnt(0)" ::: "memory");
    }
    __builtin_amdgcn_sched_barrier(0);
    __builtin_amdgcn_s_barrier();            // slot t fully staged for all waves
    __builtin_amdgcn_sched_barrier(0);
    const int sb = (t & 1) * SLOTU;
    // ---- kh = 0 ----
    short8v av[4], bv[3];
#pragma unroll
    for (int mt = 0; mt < 4; ++mt) av[mt] = *(const short8v*)&sm[sb + aoff[mt]];
#pragma unroll
    for (int nt = 0; nt < 3; ++nt) bv[nt] = *(const short8v*)&sm[sb + boff[nt]];
    __builtin_amdgcn_s_setprio(1);
#pragma unroll
    for (int mt = 0; mt < 4; ++mt)
#pragma unroll
      for (int nt = 0; nt < 3; ++nt)
        acc[mt][nt] = SWAP
          ? __builtin_amdgcn_mfma_f32_16x16x32_bf16(bv[nt], av[mt], acc[mt][nt], 0, 0, 0)
          : __builtin_amdgcn_mfma_f32_16x16x32_bf16(av[mt], bv[nt], acc[mt][nt], 0, 0, 0);
    __builtin_amdgcn_s_setprio(0);
    __builtin_amdgcn_sched_barrier(0);
    // ---- kh = 1 ----
#pragma unroll
    for (int mt = 0; mt < 4; ++mt) av[mt] = *(const short8v*)&sm[sb + aoff[mt] + 10240];
#pragma unroll
    for (int nt = 0; nt < 3; ++nt) bv[nt] = *(const short8v*)&sm[sb + boff[nt] + 10240];
    __builtin_amdgcn_s_setprio(1);
#pragma unroll
    for (int mt = 0; mt < 4; ++mt)
#pragma unroll
      for (int nt = 0; nt < 3; ++nt)
        acc[mt][nt] = SWAP
          ? __builtin_amdgcn_mfma_f32_16x16x32_bf16(bv[nt], av[mt], acc[mt][nt], 0, 0, 0)
          : __builtin_amdgcn_mfma_f32_16x16x32_bf16(av[mt], bv[nt], acc[mt][nt], 0, 0, 0);
    __builtin_amdgcn_s_setprio(0);
    __builtin_amdgcn_sched_barrier(0);
  }
  __syncthreads();   // K-loop done everywhere; sm reusable for epilogue

  if constexpr (SWAP) {
    // lane: m(local) = wm*64 + mt*16 + fr ; n(local) = wn*48 + nt*16 + g4 + j
    // dump raw acc (bf16) to padded LDS [128][200], then coalesced pass
    unsigned short* op = (unsigned short*)outp;
#pragma unroll
    for (int mt = 0; mt < 4; ++mt) {
      const int ml = wm * 64 + mt * 16 + fr;
#pragma unroll
      for (int nt = 0; nt < 3; ++nt) {
        const int nl = wn * 48 + nt * 16 + g4;
        f32x4 v = acc[mt][nt];
        ushort4v pk;
#pragma unroll
        for (int j = 0; j < 4; ++j) pk[j] = f2bf(v[j]);
        *(ushort4v*)&sm[ml * 200 + nl] = pk;
      }
    }
    __syncthreads();
#pragma unroll
    for (int it = 0; it < 6; ++it) {
      const int slot = it * 512 + tid;       // 128 rows x 24 groups
      const int row = slot / 24, grp = slot - row * 24;
      const int n = n0 + grp * 8;
      short8v v = *(const short8v*)&sm[row * 200 + grp * 8];
      if constexpr (MODE == 2) {
        const f32x4 b0 = *(const f32x4*)&bias[n];
        const f32x4 b1 = *(const f32x4*)&bias[n + 4];
#pragma unroll
        for (int e = 0; e < 8; ++e) {
          const float xv = bf2f((unsigned short)v[e]) + (e < 4 ? b0[e] : b1[e - 4]);
          v[e] = (short)f2bf(gelu_fast(xv));
        }
      } else if constexpr (MODE == 1) {
        const f32x4 b0 = *(const f32x4*)&bias[n];
        const f32x4 b1 = *(const f32x4*)&bias[n + 4];
        const short8v r8 = *(const short8v*)&resid[(size_t)(m0 + row) * C_ + n];
#pragma unroll
        for (int e = 0; e < 8; ++e)
          v[e] = (short)f2bf(bf2f((unsigned short)v[e]) + (e < 4 ? b0[e] : b1[e - 4])
                             + bf2f((unsigned short)r8[e]));
      }
      *(short8v*)&op[(size_t)(m0 + row) * NOUT + n] = v;
    }
  } else {
    // MODE 3: lane: m = m0 + wm*64 + mt*16 + g4 + j ; c = n0 + wn*48 + nt*16 + fr
    // four 48-col passes through f32 LDS [48 c][32 u], swizzled, coalesced stores
    float* lf = (float*)sm;
    float* out = (float*)outp;
#pragma unroll
    for (int q = 0; q < 4; ++q) {
      if (wn == q) {
#pragma unroll
        for (int mt = 0; mt < 4; ++mt) {
          const int u = wm * 16 + mt * 4 + g;
#pragma unroll
          for (int nt = 0; nt < 3; ++nt) {
            const int cl = nt * 16 + fr;
            const int cgl = n0 + q * 48 + cl;
            const float bo = bias[cgl];
            f32x4 v = acc[mt][nt];
#pragma unroll
            for (int j = 0; j < 4; ++j)
              v[j] = v[j] + bo + bf2f(resid[(size_t)(m0 + u * 4 + j) * C_ + cgl]);
            *(f32x4*)&lf[cl * 128 + ((u ^ (cl & 7)) << 2)] = v;
          }
        }
      }
      __syncthreads();
#pragma unroll
      for (int it = 0; it < 3; ++it) {
        const int slot = it * 512 + tid;     // 48 cols x 32 row-chunks
        const int u = slot & 31, cl = slot >> 5;
        f32x4 v = *(const f32x4*)&lf[cl * 128 + ((u ^ (cl & 7)) << 2)];
        const int cgl = n0 + q * 48 + cl;
        const int mg = m0 + u * 4;
        const int bb = mg / HW_, hw = mg - bb * HW_;
        *(f32x4*)&out[((size_t)bb * C_ + cgl) * HW_ + hw] = v;
      }
      __syncthreads();
    }
  }
}

// ---------------- multi-dilate local attention (+xn) ----------------
__global__ __launch_bounds__(256)
void attn_kernel(const unsigned short* __restrict__ qkv,
                 const unsigned short* __restrict__ xn,
                 unsigned short* __restrict__ aout) {
  const int gid = blockIdx.x * 256 + threadIdx.x;
  const int n = gid / 12;
  const int r = gid - n * 12;
  const int dil = (r >> 2) + 1;
  const int b = n / HW_;
  const int hw = n - b * HW_;
  const int h = hw / W_;
  const int w = hw - h * W_;

  const size_t base = (size_t)n * C3_ + (size_t)r * 32;
  float q[32];
  {
    const short8v* vp = (const short8v*)(qkv + base);
#pragma unroll
    for (int c8 = 0; c8 < 4; ++c8) {
      short8v v = vp[c8];
#pragma unroll
      for (int e = 0; e < 8; ++e) q[c8 * 8 + e] = bf2f((unsigned short)v[e]);
    }
  }

  float logit[9];
#pragma unroll
  for (int ti = 0; ti < 3; ++ti)
#pragma unroll
    for (int tj = 0; tj < 3; ++tj) {
      const int t = ti * 3 + tj;
      const int hn = h + (ti - 1) * dil, wn = w + (tj - 1) * dil;
      if ((unsigned)hn < 56u && (unsigned)wn < 56u) {
        const int nb = n + (ti - 1) * dil * W_ + (tj - 1) * dil;
        const short8v* kp = (const short8v*)(qkv + (size_t)nb * C3_ + C_ + (size_t)r * 32);
        float dot = 0.f;
#pragma unroll
        for (int c8 = 0; c8 < 4; ++c8) {
          short8v v = kp[c8];
#pragma unroll
          for (int e = 0; e < 8; ++e) dot += q[c8 * 8 + e] * bf2f((unsigned short)v[e]);
        }
        logit[t] = dot * 0.17677669529663688f;
      } else {
        logit[t] = 0.f;  // zero-padded taps participate with logit 0
      }
    }

  float mx = logit[0];
#pragma unroll
  for (int t = 1; t < 9; ++t) mx = fmaxf(mx, logit[t]);
  float wgt[9]; float se = 0.f;
#pragma unroll
  for (int t = 0; t < 9; ++t) { wgt[t] = __expf(logit[t] - mx); se += wgt[t]; }
  const float inv = 1.f / se;

  float acc[32];
#pragma unroll
  for (int c = 0; c < 32; ++c) acc[c] = 0.f;
#pragma unroll
  for (int ti = 0; ti < 3; ++ti)
#pragma unroll
    for (int tj = 0; tj < 3; ++tj) {
      const int t = ti * 3 + tj;
      const int hn = h + (ti - 1) * dil, wn = w + (tj - 1) * dil;
      if ((unsigned)hn < 56u && (unsigned)wn < 56u) {
        const int nb = n + (ti - 1) * dil * W_ + (tj - 1) * dil;
        const short8v* vp = (const short8v*)(qkv + (size_t)nb * C3_ + 2 * C_ + (size_t)r * 32);
        const float wt = wgt[t];
#pragma unroll
        for (int c8 = 0; c8 < 4; ++c8) {
          short8v v = vp[c8];
#pragma unroll
          for (int e = 0; e < 8; ++e) acc[c8 * 8 + e] += wt * bf2f((unsigned short)v[e]);
        }
      }
    }

  const size_t obase = (size_t)n * C_ + (size_t)r * 32;
  const short8v* xv = (const short8v*)(xn + obase);
  short8v ov[4];
#pragma unroll
  for (int c8 = 0; c8 < 4; ++c8) {
    short8v v = xv[c8];
#pragma unroll
    for (int e = 0; e < 8; ++e)
      ov[c8][e] = (short)f2bf(acc[c8 * 8 + e] * inv + bf2f((unsigned short)v[e]));
  }
  short8v* op = (short8v*)(aout + obase);
#pragma unroll
  for (int c8 = 0; c8 < 4; ++c8) op[c8] = ov[c8];
}

extern "C" void kernel_launch(void* const* d_in, const int* in_sizes, int n_in,
                              void* d_out, int out_size, void* d_ws, size_t ws_size,
                              hipStream_t stream) {
  const float* x = (const float*)d_in[0];
  const float* qkv_w = (const float*)d_in[1];
  const float* proj_w = (const float*)d_in[2];
  const float* proj_b = (const float*)d_in[3];
  const float* n1_g = (const float*)d_in[4];
  const float* n1_b = (const float*)d_in[5];
  const float* n2_g = (const float*)d_in[6];
  const float* n2_b = (const float*)d_in[7];
  const float* fc1_w = (const float*)d_in[8];
  const float* fc1_b = (const float*)d_in[9];
  const float* fc2_w = (const float*)d_in[10];
  const float* fc2_b = (const float*)d_in[11];

  char* ws = (char*)d_ws;
  unsigned short* xpb = (unsigned short*)ws;                     // [N,C] bf16 (x transposed)
  unsigned short* xn = (unsigned short*)(ws + 19267584);         // [N,C] bf16 (LN1/LN2 out)
  unsigned short* qkvb = (unsigned short*)(ws + 38535168);       // [N,1152] bf16
  unsigned short* abuf = (unsigned short*)(ws + 96337920);       // [N,C] bf16
  unsigned short* y = (unsigned short*)(ws + 115605504);         // [N,C] bf16 residual stream
  unsigned short* hbuf = qkvb;                                   // [N,1536] bf16 (reuse)
  unsigned short* wq = (unsigned short*)(ws + 134873088);        // weights bf16 [n][k]
  unsigned short* wp = wq + 442368;
  unsigned short* wf1 = wp + 147456;
  unsigned short* wf2 = wf1 + 589824;

  cvt_weights<<<6912, 256, 0, stream>>>(qkv_w, proj_w, fc1_w, fc2_w, wq);
  tpose_ln<<<392, 256, 0, stream>>>(x, xpb, xn, n1_g, n1_b);
  gemmW<0, C3_, C_><<<dim3(6, 196), 512, 0, stream>>>(xn, wq, nullptr, nullptr, qkvb);
  attn_kernel<<<1176, 256, 0, stream>>>(qkvb, xn, abuf);
  gemmW<1, C_, C_><<<dim3(2, 196), 512, 0, stream>>>(abuf, wp, proj_b, xpb, y);
  ln_rows<<<6272, 256, 0, stream>>>(y, xn, n2_g, n2_b);
  gemmW<2, HID_, C_><<<dim3(8, 196), 512, 0, stream>>>(xn, wf1, fc1_b, nullptr, hbuf);
  gemmW<3, C_, HID_><<<dim3(2, 196), 512, 0, stream>>>(hbuf, wf2, fc2_b, y, d_out);
}